// Round 2
// baseline (416.668 us; speedup 1.0000x reference)
//
#include <hip/hip_runtime.h>

#define F 64
#define F3 192
#define MAXP 256          // max pairs per atom staged in LDS (avg 32, tail-safe fallback below)
#define JSHIFT 11         // j-chunk = 2048 atoms -> x+mu slice ~3.1 MB < 4 MB per-XCD L2

// ---------------- Kernel 1: per-atom MLP  x = silu(q@W1+b1)@W2+b2 ----------------
__global__ __launch_bounds__(256) void mlp_kernel(
    const float* __restrict__ q, const float* __restrict__ W1,
    const float* __restrict__ b1, const float* __restrict__ W2,
    const float* __restrict__ b2, float* __restrict__ x, int N)
{
    __shared__ float W2s[F * F3];   // 48 KB
    __shared__ float b1s[F];
    __shared__ float b2s[F3];
    __shared__ float qs[4 * F];
    __shared__ float hs[4 * F];

    const int t = threadIdx.x;
    for (int i = t; i < F * F3; i += 256) W2s[i] = W2[i];
    if (t < F)  b1s[t] = b1[t];
    if (t < F3) b2s[t] = b2[t];
    __syncthreads();

    const int a = t >> 6;
    const int f = t & 63;
    const int ngroups = (N + 3) >> 2;

    for (int g = blockIdx.x; g < ngroups; g += gridDim.x) {
        const int atom = g * 4 + a;
        qs[t] = (atom < N) ? q[atom * F + f] : 0.f;
        __syncthreads();

        float h = b1s[f];
        #pragma unroll
        for (int k = 0; k < F; ++k)
            h = fmaf(qs[a * F + k], W1[k * F + f], h);
        h = h / (1.f + __expf(-h));   // SiLU
        hs[t] = h;
        __syncthreads();

        float acc0 = b2s[f], acc1 = b2s[F + f], acc2 = b2s[2 * F + f];
        #pragma unroll
        for (int k = 0; k < F; ++k) {
            const float hk = hs[a * F + k];
            acc0 = fmaf(hk, W2s[k * F3 + f],         acc0);
            acc1 = fmaf(hk, W2s[k * F3 + F + f],     acc1);
            acc2 = fmaf(hk, W2s[k * F3 + 2 * F + f], acc2);
        }
        if (atom < N) {
            x[atom * F3 + f]         = acc0;
            x[atom * F3 + F + f]     = acc1;
            x[atom * F3 + 2 * F + f] = acc2;
        }
        __syncthreads();
    }
}

// ---------------- Kernel 2: CSR row starts from sorted idx_i ----------------
__global__ void rowstart_kernel(const int* __restrict__ idx_i,
                                int* __restrict__ row_start, int P, int N)
{
    const int p = blockIdx.x * blockDim.x + threadIdx.x;
    if (p > P) return;
    if (p == P) {
        const int prev = idx_i[P - 1];
        for (int n = prev + 1; n <= N; ++n) row_start[n] = P;
    } else {
        const int cur  = idx_i[p];
        const int prev = (p == 0) ? -1 : idx_i[p - 1];
        for (int n = prev + 1; n <= cur; ++n) row_start[n] = p;
    }
}

// ---------------- Kernel 3: per-atom pair accumulation, j-pass blocked ----------------
// One block per atom i; thread t owns one output channel.
// idx_j for the atom's range staged in LDS; pairs processed in NPASS sweeps over
// j-chunks of 2048 atoms so concurrently-resident blocks gather from an
// L2-resident x/mu slice. Streams (Wij, dir_ij) use non-temporal loads so they
// don't evict the gather tables from L2.
__global__ __launch_bounds__(256) void accum_kernel(
    const float* __restrict__ q, const float* __restrict__ mu,
    const float* __restrict__ Wij, const float* __restrict__ dir_ij,
    const int* __restrict__ idx_j, const int* __restrict__ row_start,
    const float* __restrict__ x, float* __restrict__ out, int N)
{
    __shared__ int jbuf[MAXP];

    const int i = blockIdx.x;
    const int t = threadIdx.x;
    const int start = row_start[i];
    const int end   = row_start[i + 1];
    const int deg   = end - start;
    const int nbuf  = (deg < MAXP) ? deg : MAXP;

    for (int p = t; p < nbuf; p += 256) jbuf[p] = idx_j[start + p];
    __syncthreads();

    const int npass = ((N - 1) >> JSHIFT) + 1;

    if (t < F) {
        const int f = t;
        float acc = 0.f;
        for (int pass = 0; pass < npass; ++pass) {
            for (int p = 0; p < nbuf; ++p) {
                const int j = jbuf[p];
                if ((j >> JSHIFT) == pass) {
                    const size_t pp = (size_t)(start + p);
                    acc = fmaf(__builtin_nontemporal_load(&Wij[pp * F3 + f]),
                               x[(size_t)j * F3 + f], acc);
                }
            }
        }
        for (int p = MAXP; p < deg; ++p) {   // tail fallback (deg > MAXP: ~never)
            const int j = idx_j[start + p];
            acc = fmaf(Wij[(size_t)(start + p) * F3 + f], x[(size_t)j * F3 + f], acc);
        }
        out[(size_t)i * F + f] = __builtin_nontemporal_load(&q[(size_t)i * F + f]) + acc;
    } else {
        const int c = t - F;
        const int d = c >> 6;
        const int f = c & 63;
        float acc = 0.f;
        for (int pass = 0; pass < npass; ++pass) {
            for (int p = 0; p < nbuf; ++p) {
                const int j = jbuf[p];
                if ((j >> JSHIFT) == pass) {
                    const size_t pp = (size_t)(start + p);
                    const float vr = __builtin_nontemporal_load(&Wij[pp * F3 + F + f])
                                     * x[(size_t)j * F3 + F + f];
                    const float vm = __builtin_nontemporal_load(&Wij[pp * F3 + 2 * F + f])
                                     * x[(size_t)j * F3 + 2 * F + f];
                    acc = fmaf(vr, __builtin_nontemporal_load(&dir_ij[pp * 3 + d]), acc);
                    acc = fmaf(vm, mu[(size_t)j * F3 + d * F + f], acc);
                }
            }
        }
        for (int p = MAXP; p < deg; ++p) {   // tail fallback
            const size_t pp = (size_t)(start + p);
            const int j = idx_j[start + p];
            const float vr = Wij[pp * F3 + F + f]     * x[(size_t)j * F3 + F + f];
            const float vm = Wij[pp * F3 + 2 * F + f] * x[(size_t)j * F3 + 2 * F + f];
            acc = fmaf(vr, dir_ij[pp * 3 + d], acc);
            acc = fmaf(vm, mu[(size_t)j * F3 + d * F + f], acc);
        }
        out[(size_t)N * F + (size_t)i * F3 + c] =
            __builtin_nontemporal_load(&mu[(size_t)i * F3 + c]) + acc;
    }
}

extern "C" void kernel_launch(void* const* d_in, const int* in_sizes, int n_in,
                              void* d_out, int out_size, void* d_ws, size_t ws_size,
                              hipStream_t stream)
{
    const float* q      = (const float*)d_in[0];
    const float* mu     = (const float*)d_in[1];
    const float* Wij    = (const float*)d_in[2];
    const float* dir_ij = (const float*)d_in[3];
    const int*   idx_i  = (const int*)d_in[4];
    const int*   idx_j  = (const int*)d_in[5];
    const float* W1     = (const float*)d_in[7];
    const float* b1     = (const float*)d_in[8];
    const float* W2     = (const float*)d_in[9];
    const float* b2     = (const float*)d_in[10];

    const int N = in_sizes[0] / F;        // 20000
    const int P = in_sizes[2] / F3;       // 640000

    float* x         = (float*)d_ws;
    int*   row_start = (int*)((char*)d_ws + (size_t)N * F3 * sizeof(float));
    float* out = (float*)d_out;

    mlp_kernel<<<1280, 256, 0, stream>>>(q, W1, b1, W2, b2, x, N);
    rowstart_kernel<<<(P + 1 + 255) / 256, 256, 0, stream>>>(idx_i, row_start, P, N);
    accum_kernel<<<N, 256, 0, stream>>>(q, mu, Wij, dir_ij, idx_j, row_start, x, out, N);
}

// Round 3
// 270.629 us; speedup vs baseline: 1.5396x; 1.5396x over previous
//
#include <hip/hip_runtime.h>

#define F 64
#define F3 192
#define MAXP 256          // max pairs per atom staged/sorted in LDS (avg 32; tail fallback below)

// ---------------- Kernel 1: per-atom MLP  x = silu(q@W1+b1)@W2+b2 ----------------
__global__ __launch_bounds__(256) void mlp_kernel(
    const float* __restrict__ q, const float* __restrict__ W1,
    const float* __restrict__ b1, const float* __restrict__ W2,
    const float* __restrict__ b2, float* __restrict__ x, int N)
{
    __shared__ float W2s[F * F3];   // 48 KB
    __shared__ float b1s[F];
    __shared__ float b2s[F3];
    __shared__ float qs[4 * F];
    __shared__ float hs[4 * F];

    const int t = threadIdx.x;
    for (int i = t; i < F * F3; i += 256) W2s[i] = W2[i];
    if (t < F)  b1s[t] = b1[t];
    if (t < F3) b2s[t] = b2[t];
    __syncthreads();

    const int a = t >> 6;
    const int f = t & 63;
    const int ngroups = (N + 3) >> 2;

    for (int g = blockIdx.x; g < ngroups; g += gridDim.x) {
        const int atom = g * 4 + a;
        qs[t] = (atom < N) ? q[atom * F + f] : 0.f;
        __syncthreads();

        float h = b1s[f];
        #pragma unroll
        for (int k = 0; k < F; ++k)
            h = fmaf(qs[a * F + k], W1[k * F + f], h);
        h = h / (1.f + __expf(-h));   // SiLU
        hs[t] = h;
        __syncthreads();

        float acc0 = b2s[f], acc1 = b2s[F + f], acc2 = b2s[2 * F + f];
        #pragma unroll
        for (int k = 0; k < F; ++k) {
            const float hk = hs[a * F + k];
            acc0 = fmaf(hk, W2s[k * F3 + f],         acc0);
            acc1 = fmaf(hk, W2s[k * F3 + F + f],     acc1);
            acc2 = fmaf(hk, W2s[k * F3 + 2 * F + f], acc2);
        }
        if (atom < N) {
            x[atom * F3 + f]         = acc0;
            x[atom * F3 + F + f]     = acc1;
            x[atom * F3 + 2 * F + f] = acc2;
        }
        __syncthreads();
    }
}

// ---------------- Kernel 2: CSR row starts from sorted idx_i ----------------
__global__ void rowstart_kernel(const int* __restrict__ idx_i,
                                int* __restrict__ row_start, int P, int N)
{
    const int p = blockIdx.x * blockDim.x + threadIdx.x;
    if (p > P) return;
    if (p == P) {
        const int prev = idx_i[P - 1];
        for (int n = prev + 1; n <= N; ++n) row_start[n] = P;
    } else {
        const int cur  = idx_i[p];
        const int prev = (p == 0) ? -1 : idx_i[p - 1];
        for (int n = prev + 1; n <= cur; ++n) row_start[n] = p;
    }
}

// ---------------- Kernel 3: per-atom accumulation, j-sorted single sweep ----------------
// One block per atom i; thread t owns one output channel:
//   t in [0,64):   dq[f]
//   t in [64,256): dmu[d][f], d=(t-64)>>6, f=(t-64)&63
// The atom's pair list is staged in LDS and STABLY sorted by j (rank sort, one
// parallel O(nbuf) sweep). All resident blocks then sweep j-space in ascending
// order at similar rates, so concurrent gathers cluster in a small j-window
// (L2/L3-resident) -- round-2's locality without its multi-pass issue stall.
// Single-use streams (Wij, dir_ij, final q/mu) use non-temporal loads.
__global__ __launch_bounds__(256) void accum_kernel(
    const float* __restrict__ q, const float* __restrict__ mu,
    const float* __restrict__ Wij, const float* __restrict__ dir_ij,
    const int* __restrict__ idx_j, const int* __restrict__ row_start,
    const float* __restrict__ x, float* __restrict__ out, int N)
{
    __shared__ int jbuf[MAXP];
    __shared__ unsigned short perm[MAXP];

    const int i = blockIdx.x;
    const int t = threadIdx.x;
    const int start = row_start[i];
    const int end   = row_start[i + 1];
    const int deg   = end - start;
    const int nbuf  = (deg < MAXP) ? deg : MAXP;

    for (int p = t; p < nbuf; p += 256) jbuf[p] = idx_j[start + p];
    __syncthreads();

    // stable rank sort by j: thread t places itself at its rank
    if (t < nbuf) {
        const int myj = jbuf[t];
        int r = 0;
        for (int p = 0; p < nbuf; ++p) {
            const int jp = jbuf[p];
            r += (jp < myj) | ((jp == myj) & (p < t));
        }
        perm[r] = (unsigned short)t;
    }
    __syncthreads();

    if (t < F) {
        const int f = t;
        float acc = 0.f;
        for (int p = 0; p < nbuf; ++p) {
            const int s = perm[p];
            const int j = jbuf[s];
            const size_t pp = (size_t)(start + s);
            acc = fmaf(__builtin_nontemporal_load(&Wij[pp * F3 + f]),
                       x[(size_t)j * F3 + f], acc);
        }
        for (int p = MAXP; p < deg; ++p) {   // tail fallback (deg > MAXP: ~never)
            const int j = idx_j[start + p];
            acc = fmaf(Wij[(size_t)(start + p) * F3 + f], x[(size_t)j * F3 + f], acc);
        }
        out[(size_t)i * F + f] = __builtin_nontemporal_load(&q[(size_t)i * F + f]) + acc;
    } else {
        const int c = t - F;
        const int d = c >> 6;
        const int f = c & 63;
        float acc = 0.f;
        for (int p = 0; p < nbuf; ++p) {
            const int s = perm[p];
            const int j = jbuf[s];
            const size_t pp = (size_t)(start + s);
            const float vr = __builtin_nontemporal_load(&Wij[pp * F3 + F + f])
                             * x[(size_t)j * F3 + F + f];
            const float vm = __builtin_nontemporal_load(&Wij[pp * F3 + 2 * F + f])
                             * x[(size_t)j * F3 + 2 * F + f];
            acc = fmaf(vr, __builtin_nontemporal_load(&dir_ij[pp * 3 + d]), acc);
            acc = fmaf(vm, mu[(size_t)j * F3 + d * F + f], acc);
        }
        for (int p = MAXP; p < deg; ++p) {   // tail fallback
            const size_t pp = (size_t)(start + p);
            const int j = idx_j[start + p];
            const float vr = Wij[pp * F3 + F + f]     * x[(size_t)j * F3 + F + f];
            const float vm = Wij[pp * F3 + 2 * F + f] * x[(size_t)j * F3 + 2 * F + f];
            acc = fmaf(vr, dir_ij[pp * 3 + d], acc);
            acc = fmaf(vm, mu[(size_t)j * F3 + d * F + f], acc);
        }
        out[(size_t)N * F + (size_t)i * F3 + c] =
            __builtin_nontemporal_load(&mu[(size_t)i * F3 + c]) + acc;
    }
}

extern "C" void kernel_launch(void* const* d_in, const int* in_sizes, int n_in,
                              void* d_out, int out_size, void* d_ws, size_t ws_size,
                              hipStream_t stream)
{
    const float* q      = (const float*)d_in[0];
    const float* mu     = (const float*)d_in[1];
    const float* Wij    = (const float*)d_in[2];
    const float* dir_ij = (const float*)d_in[3];
    const int*   idx_i  = (const int*)d_in[4];
    const int*   idx_j  = (const int*)d_in[5];
    const float* W1     = (const float*)d_in[7];
    const float* b1     = (const float*)d_in[8];
    const float* W2     = (const float*)d_in[9];
    const float* b2     = (const float*)d_in[10];

    const int N = in_sizes[0] / F;        // 20000
    const int P = in_sizes[2] / F3;       // 640000

    float* x         = (float*)d_ws;
    int*   row_start = (int*)((char*)d_ws + (size_t)N * F3 * sizeof(float));
    float* out = (float*)d_out;

    mlp_kernel<<<1280, 256, 0, stream>>>(q, W1, b1, W2, b2, x, N);
    rowstart_kernel<<<(P + 1 + 255) / 256, 256, 0, stream>>>(idx_i, row_start, P, N);
    accum_kernel<<<N, 256, 0, stream>>>(q, mu, Wij, dir_ij, idx_j, row_start, x, out, N);
}

// Round 4
// 246.819 us; speedup vs baseline: 1.6882x; 1.0965x over previous
//
#include <hip/hip_runtime.h>

#define F 64
#define F3 192

// ---------------- Kernel 1: per-atom MLP  x = silu(q@W1+b1)@W2+b2 ----------------
__global__ __launch_bounds__(256) void mlp_kernel(
    const float* __restrict__ q, const float* __restrict__ W1,
    const float* __restrict__ b1, const float* __restrict__ W2,
    const float* __restrict__ b2, float* __restrict__ x, int N)
{
    __shared__ float W2s[F * F3];   // 48 KB
    __shared__ float b1s[F];
    __shared__ float b2s[F3];
    __shared__ float qs[4 * F];
    __shared__ float hs[4 * F];

    const int t = threadIdx.x;
    for (int i = t; i < F * F3; i += 256) W2s[i] = W2[i];
    if (t < F)  b1s[t] = b1[t];
    if (t < F3) b2s[t] = b2[t];
    __syncthreads();

    const int a = t >> 6;
    const int f = t & 63;
    const int ngroups = (N + 3) >> 2;

    for (int g = blockIdx.x; g < ngroups; g += gridDim.x) {
        const int atom = g * 4 + a;
        qs[t] = (atom < N) ? q[atom * F + f] : 0.f;
        __syncthreads();

        float h = b1s[f];
        #pragma unroll
        for (int k = 0; k < F; ++k)
            h = fmaf(qs[a * F + k], W1[k * F + f], h);
        h = h / (1.f + __expf(-h));   // SiLU
        hs[t] = h;
        __syncthreads();

        float acc0 = b2s[f], acc1 = b2s[F + f], acc2 = b2s[2 * F + f];
        #pragma unroll
        for (int k = 0; k < F; ++k) {
            const float hk = hs[a * F + k];
            acc0 = fmaf(hk, W2s[k * F3 + f],         acc0);
            acc1 = fmaf(hk, W2s[k * F3 + F + f],     acc1);
            acc2 = fmaf(hk, W2s[k * F3 + 2 * F + f], acc2);
        }
        if (atom < N) {
            x[atom * F3 + f]         = acc0;
            x[atom * F3 + F + f]     = acc1;
            x[atom * F3 + 2 * F + f] = acc2;
        }
        __syncthreads();
    }
}

// ---------------- Kernel 2: CSR row starts from sorted idx_i ----------------
__global__ void rowstart_kernel(const int* __restrict__ idx_i,
                                int* __restrict__ row_start, int P, int N)
{
    const int p = blockIdx.x * blockDim.x + threadIdx.x;
    if (p > P) return;
    if (p == P) {
        const int prev = idx_i[P - 1];
        for (int n = prev + 1; n <= N; ++n) row_start[n] = P;
    } else {
        const int cur  = idx_i[p];
        const int prev = (p == 0) ? -1 : idx_i[p - 1];
        for (int n = prev + 1; n <= cur; ++n) row_start[n] = p;
    }
}

// ---------------- Kernel 3: per-atom accumulation, 1 wave per atom ----------------
// Block = 256 threads = 4 waves = 4 atoms. Lane f owns channels dq[f],
// dmu[0][f], dmu[1][f], dmu[2][f]. Per pair: 9 coalesced 256B vector loads
// (3x Wij nontemporal, 3x x-gather, 3x mu-gather) + wave-uniform scalar loads
// for j and dir_ij. No LDS, no syncthreads, no atomics (CSR from sorted idx_i).
__global__ __launch_bounds__(256) void accum_kernel(
    const float* __restrict__ q, const float* __restrict__ mu,
    const float* __restrict__ Wij, const float* __restrict__ dir_ij,
    const int* __restrict__ idx_j, const int* __restrict__ row_start,
    const float* __restrict__ x, float* __restrict__ out, int N)
{
    const int a = blockIdx.x * 4 + (threadIdx.x >> 6);   // atom (wave-uniform)
    const int f = threadIdx.x & 63;                      // channel
    if (a >= N) return;

    const int start = __builtin_amdgcn_readfirstlane(row_start[a]);
    const int end   = __builtin_amdgcn_readfirstlane(row_start[a + 1]);

    float dq = 0.f, dm0 = 0.f, dm1 = 0.f, dm2 = 0.f;

    #pragma unroll 2
    for (int p = start; p < end; ++p) {
        const int j = __builtin_amdgcn_readfirstlane(idx_j[p]);  // s_load + SGPR addr math

        const float* wp = Wij + (size_t)p * F3;
        const float* xp = x   + (size_t)j * F3;
        const float* mp = mu  + (size_t)j * F3;

        const float wq = __builtin_nontemporal_load(wp + f);
        const float wr = __builtin_nontemporal_load(wp + F + f);
        const float wm = __builtin_nontemporal_load(wp + 2 * F + f);
        const float xq = xp[f];
        const float xr = xp[F + f];
        const float xm = xp[2 * F + f];
        const float m0 = mp[f];
        const float m1 = mp[F + f];
        const float m2 = mp[2 * F + f];
        const float d0 = dir_ij[p * 3 + 0];   // wave-uniform -> s_load
        const float d1 = dir_ij[p * 3 + 1];
        const float d2 = dir_ij[p * 3 + 2];

        dq = fmaf(wq, xq, dq);
        const float vr = wr * xr;
        const float vm = wm * xm;
        dm0 = fmaf(vr, d0, fmaf(vm, m0, dm0));
        dm1 = fmaf(vr, d1, fmaf(vm, m1, dm1));
        dm2 = fmaf(vr, d2, fmaf(vm, m2, dm2));
    }

    out[(size_t)a * F + f] = __builtin_nontemporal_load(q + (size_t)a * F + f) + dq;
    float*       om = out + (size_t)N * F + (size_t)a * F3;
    const float* mi = mu  + (size_t)a * F3;
    om[f]         = __builtin_nontemporal_load(mi + f)         + dm0;
    om[F + f]     = __builtin_nontemporal_load(mi + F + f)     + dm1;
    om[2 * F + f] = __builtin_nontemporal_load(mi + 2 * F + f) + dm2;
}

extern "C" void kernel_launch(void* const* d_in, const int* in_sizes, int n_in,
                              void* d_out, int out_size, void* d_ws, size_t ws_size,
                              hipStream_t stream)
{
    const float* q      = (const float*)d_in[0];
    const float* mu     = (const float*)d_in[1];
    const float* Wij    = (const float*)d_in[2];
    const float* dir_ij = (const float*)d_in[3];
    const int*   idx_i  = (const int*)d_in[4];
    const int*   idx_j  = (const int*)d_in[5];
    const float* W1     = (const float*)d_in[7];
    const float* b1     = (const float*)d_in[8];
    const float* W2     = (const float*)d_in[9];
    const float* b2     = (const float*)d_in[10];

    const int N = in_sizes[0] / F;        // 20000
    const int P = in_sizes[2] / F3;       // 640000

    float* x         = (float*)d_ws;
    int*   row_start = (int*)((char*)d_ws + (size_t)N * F3 * sizeof(float));
    float* out = (float*)d_out;

    mlp_kernel<<<1280, 256, 0, stream>>>(q, W1, b1, W2, b2, x, N);
    rowstart_kernel<<<(P + 1 + 255) / 256, 256, 0, stream>>>(idx_i, row_start, P, N);
    accum_kernel<<<(N + 3) / 4, 256, 0, stream>>>(q, mu, Wij, dir_ij, idx_j, row_start, x, out, N);
}